// Round 9
// baseline (400.869 us; speedup 1.0000x reference)
//
#include <hip/hip_runtime.h>

#define SPK 1024
#define UTT 64
#define DIM 256
#define EPSV 1e-5f
#define NROW (SPK * UTT)
#define NSL 16           // column slices (64 cols each)
#define LOG2E 1.44269504f

typedef __attribute__((ext_vector_type(8))) short short8;   // 8 bf16 (4 VGPRs)
typedef __attribute__((ext_vector_type(4))) float f32x4;    // MFMA accumulator

__device__ __forceinline__ unsigned short f2bf(float f) {
    unsigned int u = __builtin_bit_cast(unsigned int, f);
    u += 0x7fffu + ((u >> 16) & 1u);          // round-to-nearest-even
    return (unsigned short)(u >> 16);
}

// K1: one block (256 thr) per speaker. Phase A: csum + c_incl (bf16) + ||csum||^2.
// Phase B: 4 lanes per row (quad-reduce), x re-read L2-hot, writes e_n (bf16)
// and pre-scaled diagonal logit texcl = w*sim_excl + b.
__global__ __launch_bounds__(256)
void k_prep(const float* __restrict__ x,
            unsigned short* __restrict__ cincl,
            unsigned short* __restrict__ en,
            float* __restrict__ texcl,
            const float* __restrict__ wp, const float* __restrict__ bp) {
    __shared__ float4 sc4[256];
    __shared__ float4 cs4[64];
    __shared__ float sccs;
    int s = blockIdx.x, tid = threadIdx.x;
    int dq = tid & 63, ug = tid >> 6;
    const float4* x4 = (const float4*)(x + (size_t)s * UTT * DIM);

    // Phase A: column sums over the 64 utterances (coalesced 1KB/instr)
    float4 p = {0.f, 0.f, 0.f, 0.f};
#pragma unroll
    for (int i = 0; i < 16; ++i) {
        float4 v = x4[(ug * 16 + i) * 64 + dq];
        p.x += v.x; p.y += v.y; p.z += v.z; p.w += v.w;
    }
    sc4[tid] = p;
    __syncthreads();
    if (tid < 64) {
        float4 a = sc4[dq], b2 = sc4[64 + dq], c = sc4[128 + dq], d = sc4[192 + dq];
        float4 cs = {a.x + b2.x + c.x + d.x, a.y + b2.y + c.y + d.y,
                     a.z + b2.z + c.z + d.z, a.w + b2.w + c.w + d.w};
        cs4[dq] = cs;
        float s2 = cs.x * cs.x + cs.y * cs.y + cs.z * cs.z + cs.w * cs.w;
#pragma unroll
        for (int o = 1; o < 64; o <<= 1) s2 += __shfl_xor(s2, o);
        if (tid == 0) sccs = s2;
        // c_incl = (csum/U)/(||csum/U||+eps) == csum/(||csum|| + U*eps)
        float inv = 1.f / (sqrtf(s2) + UTT * EPSV);
        ushort4 ob = {f2bf(cs.x * inv), f2bf(cs.y * inv),
                      f2bf(cs.z * inv), f2bf(cs.w * inv)};
        *(ushort4*)(cincl + (size_t)s * DIM + dq * 4) = ob;
    }
    __syncthreads();
    float scc = sccs;
    float w = wp[0], b = bp[0];

    // Phase B: row = tid>>2 (64 rows), sub = tid&3 (4 lanes per row).
    int row = tid >> 2, sub = tid & 3;
    const float4* xr = x4 + row * 64;
    float4 xv[16];
    float sx = 0.f, sc = 0.f;
#pragma unroll
    for (int i = 0; i < 16; ++i) {
        float4 v = xr[i * 4 + sub];
        float4 cv = cs4[i * 4 + sub];
        xv[i] = v;
        sx += v.x * v.x + v.y * v.y + v.z * v.z + v.w * v.w;
        sc += v.x * cv.x + v.y * cv.y + v.z * cv.z + v.w * cv.w;
    }
    // quad reduce: all 4 lanes of the row end up with the totals
    sx += __shfl_xor(sx, 1); sx += __shfl_xor(sx, 2);
    sc += __shfl_xor(sc, 1); sc += __shfl_xor(sc, 2);
    float nx = sqrtf(sx);
    float inv = 1.f / (nx + EPSV);
    unsigned short* er = en + (size_t)(s * UTT + row) * DIM;
#pragma unroll
    for (int i = 0; i < 16; ++i) {
        ushort4 ob = {f2bf(xv[i].x * inv), f2bf(xv[i].y * inv),
                      f2bf(xv[i].z * inv), f2bf(xv[i].w * inv)};
        *(ushort4*)(er + (i * 4 + sub) * 4) = ob;
    }
    if (sub == 0) {
        // sim_excl = x.(csum-x) / ((||x||+eps)(||csum-x||+63eps))
        float num = sc - sx;
        float e2 = fmaxf(scc - 2.f * sc + sx, 0.f);
        float sim = num / ((nx + EPSV) * (sqrtf(e2) + (UTT - 1) * EPSV));
        texcl[s * UTT + row] = fmaf(sim, w, b);
    }
}

// K2: block = 4 speakers x one 64-col slice; B slice (32 KB) staged into LDS
// once (ONE barrier per block), then 4 ntiles of ds_read+MFMA+exp2. 32 KB LDS
// -> 4 blocks/CU resident (vs 2 at 64 KB): stalls of one block hidden by the
// other three. XCD swizzle: bid%8 = XCD; cs = j&15, sg = xcd + 8*(j>>4) so all
// 16 slices of a speaker group run back-to-back on ONE XCD -> A tile L2-hot.
__global__ __launch_bounds__(256, 4)
void k_main(const unsigned short* __restrict__ en,
            const unsigned short* __restrict__ cincl,
            float* __restrict__ partial,
            const float* __restrict__ wp, const float* __restrict__ bp) {
    __shared__ unsigned short Bs[32 * 512];      // 32 slots x 1 KB = 32 KB
    int tid = threadIdx.x, wave = tid >> 6, lane = tid & 63;
    int quad = lane >> 4, lx = lane & 15;
    int bid = blockIdx.x;
    int xcd = bid & 7, j = bid >> 3;             // j in [0,512)
    int cs = j & 15;                             // column slice (0..15)
    int sg = xcd + 8 * (j >> 4);                 // speaker group (0..255)
    int sw = sg * 4 + wave;                      // this wave's speaker
    float w = wp[0], b = bp[0];
    float M  = fabsf(w) * 1.0625f + b;           // >= any logit (|sim| <= ~1)
    float wl = w * LOG2E;
    float bl = (b - M) * LOG2E;                  // exp(v-M) = exp2(acc*wl + bl)

    // stage B: slot p=(nt*8+kt); wave w stages ntile w's 8 k-slots.
    // lane ℓ supplies B[n = cs*64 + nt*16 + (ℓ&15)][k = kt*32 + (ℓ>>4)*8 ..+8]
#pragma unroll
    for (int kt = 0; kt < 8; ++kt) {
        const unsigned short* g = cincl +
            (size_t)(cs * 64 + wave * 16 + lx) * DIM + kt * 32 + quad * 8;
        __builtin_amdgcn_global_load_lds(
            (const __attribute__((address_space(1))) void*)g,
            (__attribute__((address_space(3))) void*)(Bs + (wave * 8 + kt) * 512),
            16, 0, 0);
    }

    // A fragments (64 rows of speaker sw) while staging is in flight
    const unsigned short* abase = en + (size_t)sw * UTT * DIM;
    short8 af[4][8];
#pragma unroll
    for (int mt = 0; mt < 4; ++mt)
#pragma unroll
        for (int kt = 0; kt < 8; ++kt)
            af[mt][kt] = *(const short8*)(abase + (mt * 16 + lx) * DIM + kt * 32 + quad * 8);

    float l[16];
#pragma unroll
    for (int i = 0; i < 16; ++i) l[i] = 0.f;

    __syncthreads();

    int dnt = (sw >> 4) - cs * 4;                // diag ntile if in [0,4)
    int dlx = sw & 15;

#pragma unroll
    for (int nt = 0; nt < 4; ++nt) {
        short8 bf[8];
#pragma unroll
        for (int kt = 0; kt < 8; ++kt)
            bf[kt] = *(const short8*)(Bs + (nt * 8 + kt) * 512 + lane * 8);
        f32x4 aA[4] = {{0.f,0.f,0.f,0.f},{0.f,0.f,0.f,0.f},
                       {0.f,0.f,0.f,0.f},{0.f,0.f,0.f,0.f}};
        f32x4 aB[4] = {{0.f,0.f,0.f,0.f},{0.f,0.f,0.f,0.f},
                       {0.f,0.f,0.f,0.f},{0.f,0.f,0.f,0.f}};
#pragma unroll
        for (int kt = 0; kt < 4; ++kt) {         // 8 interleaved MFMA chains
            aA[0] = __builtin_amdgcn_mfma_f32_16x16x32_bf16(af[0][kt], bf[kt], aA[0], 0, 0, 0);
            aA[1] = __builtin_amdgcn_mfma_f32_16x16x32_bf16(af[1][kt], bf[kt], aA[1], 0, 0, 0);
            aA[2] = __builtin_amdgcn_mfma_f32_16x16x32_bf16(af[2][kt], bf[kt], aA[2], 0, 0, 0);
            aA[3] = __builtin_amdgcn_mfma_f32_16x16x32_bf16(af[3][kt], bf[kt], aA[3], 0, 0, 0);
            aB[0] = __builtin_amdgcn_mfma_f32_16x16x32_bf16(af[0][kt+4], bf[kt+4], aB[0], 0, 0, 0);
            aB[1] = __builtin_amdgcn_mfma_f32_16x16x32_bf16(af[1][kt+4], bf[kt+4], aB[1], 0, 0, 0);
            aB[2] = __builtin_amdgcn_mfma_f32_16x16x32_bf16(af[2][kt+4], bf[kt+4], aB[2], 0, 0, 0);
            aB[3] = __builtin_amdgcn_mfma_f32_16x16x32_bf16(af[3][kt+4], bf[kt+4], aB[3], 0, 0, 0);
        }
#pragma unroll
        for (int mt = 0; mt < 4; ++mt)
#pragma unroll
            for (int r = 0; r < 4; ++r)
                l[mt * 4 + r] += exp2f(fmaf(aA[mt][r] + aB[mt][r], wl, bl));
        if (nt == dnt) {                          // wave-uniform: undo diag col
#pragma unroll
            for (int mt = 0; mt < 4; ++mt)
#pragma unroll
                for (int r = 0; r < 4; ++r) {
                    float e = exp2f(fmaf(aA[mt][r] + aB[mt][r], wl, bl));
                    if (lx == dlx) l[mt * 4 + r] -= e;
                }
        }
    }

    // reduce over the 16 col-lanes; rows live at (quad, mt, r)
#pragma unroll
    for (int o = 1; o < 16; o <<= 1)
#pragma unroll
        for (int i = 0; i < 16; ++i) l[i] += __shfl_xor(l[i], o);
    if (lx == 0)
#pragma unroll
        for (int mt = 0; mt < 4; ++mt)
#pragma unroll
            for (int r = 0; r < 4; ++r)
                partial[(size_t)cs * NROW + (size_t)sw * UTT + mt * 16 + quad * 4 + r]
                    = l[mt * 4 + r];
}

// K3: combine the 16 slice partials per row, logsumexp, mean-reduce.
__global__ __launch_bounds__(256)
void k_final(const float* __restrict__ partial, const float* __restrict__ texcl,
             const float* __restrict__ wp, const float* __restrict__ bp,
             float* __restrict__ out) {
    int row = blockIdx.x * 256 + threadIdx.x;
    float w = wp[0], b = bp[0];
    float M = fabsf(w) * 1.0625f + b;
    float t = 0.f;
#pragma unroll
    for (int sl = 0; sl < NSL; ++sl) t += partial[(size_t)sl * NROW + row];
    float tex = texcl[row];
    float c = (M + __logf(t + exp2f((tex - M) * LOG2E))) - tex;   // lse - target
#pragma unroll
    for (int o = 1; o < 64; o <<= 1) c += __shfl_xor(c, o);
    __shared__ float red[4];
    if ((threadIdx.x & 63) == 0) red[threadIdx.x >> 6] = c;
    __syncthreads();
    if (threadIdx.x == 0)
        atomicAdd(out, (red[0] + red[1] + red[2] + red[3]) * (1.f / NROW));
}

extern "C" void kernel_launch(void* const* d_in, const int* in_sizes, int n_in,
                              void* d_out, int out_size, void* d_ws, size_t ws_size,
                              hipStream_t stream) {
    const float* x  = (const float*)d_in[0];
    const float* wp = (const float*)d_in[1];
    const float* bp = (const float*)d_in[2];
    char* ws = (char*)d_ws;
    unsigned short* cincl = (unsigned short*)ws;                    // @0,    512 KB
    float* texcl          = (float*)(ws + (1u << 19));              // @512K, 256 KB
    float* partial        = (float*)(ws + (3u << 20));              // @3M,   4 MB
    unsigned short* en    = (unsigned short*)(ws + (8u << 20));     // @8M,   32 MB
    float* out = (float*)d_out;

    hipMemsetAsync(d_out, 0, sizeof(float), stream);
    k_prep <<<SPK, 256, 0, stream>>>(x, cincl, en, texcl, wp, bp);
    k_main <<<(SPK / 4) * NSL, 256, 0, stream>>>(en, cincl, partial, wp, bp);
    k_final<<<NROW / 256, 256, 0, stream>>>(partial, texcl, wp, bp, out);
}

// Round 10
// 244.248 us; speedup vs baseline: 1.6412x; 1.6412x over previous
//
#include <hip/hip_runtime.h>

#define SPK 1024
#define UTT 64
#define DIM 256
#define EPSV 1e-5f
#define NROW (SPK * UTT)
#define NSL 16           // column slices (64 cols each)
#define LOG2E 1.44269504f

typedef __attribute__((ext_vector_type(8))) short short8;   // 8 bf16 (4 VGPRs)
typedef __attribute__((ext_vector_type(4))) float f32x4;    // MFMA accumulator

#define EXP2(x) __builtin_amdgcn_exp2f(x)     // bare v_exp_f32, no libm guards

__device__ __forceinline__ unsigned short f2bf(float f) {
    unsigned int u = __builtin_bit_cast(unsigned int, f);
    u += 0x7fffu + ((u >> 16) & 1u);          // round-to-nearest-even
    return (unsigned short)(u >> 16);
}

// K1: one block (256 thr) per speaker. Phase A: csum + c_incl (bf16) + ||csum||^2.
// Phase B: 4 lanes per row (quad-reduce), x re-read L2-hot, writes e_n (bf16)
// and pre-scaled diagonal logit texcl = w*sim_excl + b.
__global__ __launch_bounds__(256)
void k_prep(const float* __restrict__ x,
            unsigned short* __restrict__ cincl,
            unsigned short* __restrict__ en,
            float* __restrict__ texcl,
            const float* __restrict__ wp, const float* __restrict__ bp) {
    __shared__ float4 sc4[256];
    __shared__ float4 cs4[64];
    __shared__ float sccs;
    int s = blockIdx.x, tid = threadIdx.x;
    int dq = tid & 63, ug = tid >> 6;
    const float4* x4 = (const float4*)(x + (size_t)s * UTT * DIM);

    // Phase A: column sums over the 64 utterances (coalesced 1KB/instr)
    float4 p = {0.f, 0.f, 0.f, 0.f};
#pragma unroll
    for (int i = 0; i < 16; ++i) {
        float4 v = x4[(ug * 16 + i) * 64 + dq];
        p.x += v.x; p.y += v.y; p.z += v.z; p.w += v.w;
    }
    sc4[tid] = p;
    __syncthreads();
    if (tid < 64) {
        float4 a = sc4[dq], b2 = sc4[64 + dq], c = sc4[128 + dq], d = sc4[192 + dq];
        float4 cs = {a.x + b2.x + c.x + d.x, a.y + b2.y + c.y + d.y,
                     a.z + b2.z + c.z + d.z, a.w + b2.w + c.w + d.w};
        cs4[dq] = cs;
        float s2 = cs.x * cs.x + cs.y * cs.y + cs.z * cs.z + cs.w * cs.w;
#pragma unroll
        for (int o = 1; o < 64; o <<= 1) s2 += __shfl_xor(s2, o);
        if (tid == 0) sccs = s2;
        // c_incl = (csum/U)/(||csum/U||+eps) == csum/(||csum|| + U*eps)
        float inv = 1.f / (sqrtf(s2) + UTT * EPSV);
        ushort4 ob = {f2bf(cs.x * inv), f2bf(cs.y * inv),
                      f2bf(cs.z * inv), f2bf(cs.w * inv)};
        *(ushort4*)(cincl + (size_t)s * DIM + dq * 4) = ob;
    }
    __syncthreads();
    float scc = sccs;
    float w = wp[0], b = bp[0];

    // Phase B: row = tid>>2 (64 rows), sub = tid&3 (4 lanes per row).
    int row = tid >> 2, sub = tid & 3;
    const float4* xr = x4 + row * 64;
    float4 xv[16];
    float sx = 0.f, sc = 0.f;
#pragma unroll
    for (int i = 0; i < 16; ++i) {
        float4 v = xr[i * 4 + sub];
        float4 cv = cs4[i * 4 + sub];
        xv[i] = v;
        sx += v.x * v.x + v.y * v.y + v.z * v.z + v.w * v.w;
        sc += v.x * cv.x + v.y * cv.y + v.z * cv.z + v.w * cv.w;
    }
    // quad reduce: all 4 lanes of the row end up with the totals
    sx += __shfl_xor(sx, 1); sx += __shfl_xor(sx, 2);
    sc += __shfl_xor(sc, 1); sc += __shfl_xor(sc, 2);
    float nx = sqrtf(sx);
    float inv = 1.f / (nx + EPSV);
    unsigned short* er = en + (size_t)(s * UTT + row) * DIM;
#pragma unroll
    for (int i = 0; i < 16; ++i) {
        ushort4 ob = {f2bf(xv[i].x * inv), f2bf(xv[i].y * inv),
                      f2bf(xv[i].z * inv), f2bf(xv[i].w * inv)};
        *(ushort4*)(er + (i * 4 + sub) * 4) = ob;
    }
    if (sub == 0) {
        // sim_excl = x.(csum-x) / ((||x||+eps)(||csum-x||+63eps))
        float num = sc - sx;
        float e2 = fmaxf(scc - 2.f * sc + sx, 0.f);
        float sim = num / ((nx + EPSV) * (sqrtf(e2) + (UTT - 1) * EPSV));
        texcl[s * UTT + row] = fmaf(sim, w, b);
    }
}

// K2: block = 4 speakers x one 64-col slice; B slice (32 KB) staged into LDS
// once (ONE barrier per block), then 4 ntiles of ds_read+MFMA+exp2.
// launch_bounds(256,3): 3 blocks/CU (96 KB LDS, VGPR cap 170 — above the
// ~140 actually needed, so NO spill) -> 3 independent waves/SIMD whose
// MFMA/VALU phases decorrelate and overlap. XCD swizzle: bid%8 = XCD;
// cs = j&15, sg = xcd + 8*(j>>4): all 16 slices of a group on one XCD.
__global__ __launch_bounds__(256, 3)
void k_main(const unsigned short* __restrict__ en,
            const unsigned short* __restrict__ cincl,
            float* __restrict__ partial,
            const float* __restrict__ wp, const float* __restrict__ bp) {
    __shared__ unsigned short Bs[32 * 512];      // 32 slots x 1 KB = 32 KB
    int tid = threadIdx.x, wave = tid >> 6, lane = tid & 63;
    int quad = lane >> 4, lx = lane & 15;
    int bid = blockIdx.x;
    int xcd = bid & 7, j = bid >> 3;             // j in [0,512)
    int cs = j & 15;                             // column slice (0..15)
    int sg = xcd + 8 * (j >> 4);                 // speaker group (0..255)
    int sw = sg * 4 + wave;                      // this wave's speaker
    float w = wp[0], b = bp[0];
    float M  = fabsf(w) * 1.0625f + b;           // >= any logit (|sim| <= ~1)
    float wl = w * LOG2E;
    float bl = (b - M) * LOG2E;                  // exp(v-M) = exp2(acc*wl + bl)

    // stage B: slot p=(nt*8+kt); wave w stages ntile w's 8 k-slots.
    // lane ℓ supplies B[n = cs*64 + nt*16 + (ℓ&15)][k = kt*32 + (ℓ>>4)*8 ..+8]
#pragma unroll
    for (int kt = 0; kt < 8; ++kt) {
        const unsigned short* g = cincl +
            (size_t)(cs * 64 + wave * 16 + lx) * DIM + kt * 32 + quad * 8;
        __builtin_amdgcn_global_load_lds(
            (const __attribute__((address_space(1))) void*)g,
            (__attribute__((address_space(3))) void*)(Bs + (wave * 8 + kt) * 512),
            16, 0, 0);
    }

    // A fragments (64 rows of speaker sw) while staging is in flight
    const unsigned short* abase = en + (size_t)sw * UTT * DIM;
    short8 af[4][8];
#pragma unroll
    for (int mt = 0; mt < 4; ++mt)
#pragma unroll
        for (int kt = 0; kt < 8; ++kt)
            af[mt][kt] = *(const short8*)(abase + (mt * 16 + lx) * DIM + kt * 32 + quad * 8);

    float l[16];
#pragma unroll
    for (int i = 0; i < 16; ++i) l[i] = 0.f;

    __syncthreads();

    int dnt = (sw >> 4) - cs * 4;                // diag ntile if in [0,4)
    int dlx = sw & 15;

#pragma unroll
    for (int nt = 0; nt < 4; ++nt) {
        short8 bf[8];
#pragma unroll
        for (int kt = 0; kt < 8; ++kt)
            bf[kt] = *(const short8*)(Bs + (nt * 8 + kt) * 512 + lane * 8);
        f32x4 aA[4] = {{0.f,0.f,0.f,0.f},{0.f,0.f,0.f,0.f},
                       {0.f,0.f,0.f,0.f},{0.f,0.f,0.f,0.f}};
        f32x4 aB[4] = {{0.f,0.f,0.f,0.f},{0.f,0.f,0.f,0.f},
                       {0.f,0.f,0.f,0.f},{0.f,0.f,0.f,0.f}};
#pragma unroll
        for (int kt = 0; kt < 4; ++kt) {         // 8 interleaved MFMA chains
            aA[0] = __builtin_amdgcn_mfma_f32_16x16x32_bf16(af[0][kt], bf[kt], aA[0], 0, 0, 0);
            aA[1] = __builtin_amdgcn_mfma_f32_16x16x32_bf16(af[1][kt], bf[kt], aA[1], 0, 0, 0);
            aA[2] = __builtin_amdgcn_mfma_f32_16x16x32_bf16(af[2][kt], bf[kt], aA[2], 0, 0, 0);
            aA[3] = __builtin_amdgcn_mfma_f32_16x16x32_bf16(af[3][kt], bf[kt], aA[3], 0, 0, 0);
            aB[0] = __builtin_amdgcn_mfma_f32_16x16x32_bf16(af[0][kt+4], bf[kt+4], aB[0], 0, 0, 0);
            aB[1] = __builtin_amdgcn_mfma_f32_16x16x32_bf16(af[1][kt+4], bf[kt+4], aB[1], 0, 0, 0);
            aB[2] = __builtin_amdgcn_mfma_f32_16x16x32_bf16(af[2][kt+4], bf[kt+4], aB[2], 0, 0, 0);
            aB[3] = __builtin_amdgcn_mfma_f32_16x16x32_bf16(af[3][kt+4], bf[kt+4], aB[3], 0, 0, 0);
        }
#pragma unroll
        for (int mt = 0; mt < 4; ++mt)
#pragma unroll
            for (int r = 0; r < 4; ++r)
                l[mt * 4 + r] += EXP2(fmaf(aA[mt][r] + aB[mt][r], wl, bl));
        if (nt == dnt) {                          // wave-uniform: undo diag col
#pragma unroll
            for (int mt = 0; mt < 4; ++mt)
#pragma unroll
                for (int r = 0; r < 4; ++r) {
                    float e = EXP2(fmaf(aA[mt][r] + aB[mt][r], wl, bl));
                    if (lx == dlx) l[mt * 4 + r] -= e;
                }
        }
    }

    // reduce over the 16 col-lanes; rows live at (quad, mt, r)
#pragma unroll
    for (int o = 1; o < 16; o <<= 1)
#pragma unroll
        for (int i = 0; i < 16; ++i) l[i] += __shfl_xor(l[i], o);
    if (lx == 0)
#pragma unroll
        for (int mt = 0; mt < 4; ++mt)
#pragma unroll
            for (int r = 0; r < 4; ++r)
                partial[(size_t)cs * NROW + (size_t)sw * UTT + mt * 16 + quad * 4 + r]
                    = l[mt * 4 + r];
}

// K3: combine the 16 slice partials per row, logsumexp, mean-reduce.
__global__ __launch_bounds__(256)
void k_final(const float* __restrict__ partial, const float* __restrict__ texcl,
             const float* __restrict__ wp, const float* __restrict__ bp,
             float* __restrict__ out) {
    int row = blockIdx.x * 256 + threadIdx.x;
    float w = wp[0], b = bp[0];
    float M = fabsf(w) * 1.0625f + b;
    float t = 0.f;
#pragma unroll
    for (int sl = 0; sl < NSL; ++sl) t += partial[(size_t)sl * NROW + row];
    float tex = texcl[row];
    float c = (M + __logf(t + EXP2((tex - M) * LOG2E))) - tex;   // lse - target
#pragma unroll
    for (int o = 1; o < 64; o <<= 1) c += __shfl_xor(c, o);
    __shared__ float red[4];
    if ((threadIdx.x & 63) == 0) red[threadIdx.x >> 6] = c;
    __syncthreads();
    if (threadIdx.x == 0)
        atomicAdd(out, (red[0] + red[1] + red[2] + red[3]) * (1.f / NROW));
}

extern "C" void kernel_launch(void* const* d_in, const int* in_sizes, int n_in,
                              void* d_out, int out_size, void* d_ws, size_t ws_size,
                              hipStream_t stream) {
    const float* x  = (const float*)d_in[0];
    const float* wp = (const float*)d_in[1];
    const float* bp = (const float*)d_in[2];
    char* ws = (char*)d_ws;
    unsigned short* cincl = (unsigned short*)ws;                    // @0,    512 KB
    float* texcl          = (float*)(ws + (1u << 19));              // @512K, 256 KB
    float* partial        = (float*)(ws + (3u << 20));              // @3M,   4 MB
    unsigned short* en    = (unsigned short*)(ws + (8u << 20));     // @8M,   32 MB
    float* out = (float*)d_out;

    hipMemsetAsync(d_out, 0, sizeof(float), stream);
    k_prep <<<SPK, 256, 0, stream>>>(x, cincl, en, texcl, wp, bp);
    k_main <<<(SPK / 4) * NSL, 256, 0, stream>>>(en, cincl, partial, wp, bp);
    k_final<<<NROW / 256, 256, 0, stream>>>(partial, texcl, wp, bp, out);
}

// Round 11
// 196.058 us; speedup vs baseline: 2.0446x; 1.2458x over previous
//
#include <hip/hip_runtime.h>

#define SPK 1024
#define UTT 64
#define DIM 256
#define EPSV 1e-5f
#define NROW (SPK * UTT)
#define NSL 8            // column slices (128 cols each)
#define LOG2E 1.44269504f

typedef __attribute__((ext_vector_type(4))) float f32x4;    // MFMA accumulator

#define EXP2(x) __builtin_amdgcn_exp2f(x)     // bare v_exp_f32, no libm guards

// pack 4 floats -> 4 fp8 e4m3 bytes
__device__ __forceinline__ int pk_fp8(float a, float b, float c, float d) {
    int v = __builtin_amdgcn_cvt_pk_fp8_f32(a, b, 0, false);   // bytes 0,1
    return  __builtin_amdgcn_cvt_pk_fp8_f32(c, d, v, true);    // bytes 2,3
}

// K1: one block (256 thr) per speaker. Phase A: csum + c_incl (fp8, x16 scale)
// + ||csum||^2. Phase B: 4 lanes per row (quad-reduce), x re-read L2-hot,
// writes e_n (fp8, x16 scale) and fp32 diagonal logit texcl = w*sim_excl + b.
__global__ __launch_bounds__(256)
void k_prep(const float* __restrict__ x,
            unsigned char* __restrict__ cincl8,
            unsigned char* __restrict__ en8,
            float* __restrict__ texcl,
            const float* __restrict__ wp, const float* __restrict__ bp) {
    __shared__ float4 sc4[256];
    __shared__ float4 cs4[64];
    __shared__ float sccs;
    int s = blockIdx.x, tid = threadIdx.x;
    int dq = tid & 63, ug = tid >> 6;
    const float4* x4 = (const float4*)(x + (size_t)s * UTT * DIM);

    // Phase A: column sums over the 64 utterances (coalesced 1KB/instr)
    float4 p = {0.f, 0.f, 0.f, 0.f};
#pragma unroll
    for (int i = 0; i < 16; ++i) {
        float4 v = x4[(ug * 16 + i) * 64 + dq];
        p.x += v.x; p.y += v.y; p.z += v.z; p.w += v.w;
    }
    sc4[tid] = p;
    __syncthreads();
    if (tid < 64) {
        float4 a = sc4[dq], b2 = sc4[64 + dq], c = sc4[128 + dq], d = sc4[192 + dq];
        float4 cs = {a.x + b2.x + c.x + d.x, a.y + b2.y + c.y + d.y,
                     a.z + b2.z + c.z + d.z, a.w + b2.w + c.w + d.w};
        cs4[dq] = cs;
        float s2 = cs.x * cs.x + cs.y * cs.y + cs.z * cs.z + cs.w * cs.w;
#pragma unroll
        for (int o = 1; o < 64; o <<= 1) s2 += __shfl_xor(s2, o);
        if (tid == 0) sccs = s2;
        // c_incl = csum/(||csum|| + U*eps), quantized x16 into e4m3
        float inv = 16.f / (sqrtf(s2) + UTT * EPSV);
        ((int*)cincl8)[s * 64 + dq] =
            pk_fp8(cs.x * inv, cs.y * inv, cs.z * inv, cs.w * inv);
    }
    __syncthreads();
    float scc = sccs;
    float w = wp[0], b = bp[0];

    // Phase B: row = tid>>2 (64 rows), sub = tid&3 (4 lanes per row).
    int row = tid >> 2, sub = tid & 3;
    const float4* xr = x4 + row * 64;
    float4 xv[16];
    float sx = 0.f, sc = 0.f;
#pragma unroll
    for (int i = 0; i < 16; ++i) {
        float4 v = xr[i * 4 + sub];
        float4 cv = cs4[i * 4 + sub];
        xv[i] = v;
        sx += v.x * v.x + v.y * v.y + v.z * v.z + v.w * v.w;
        sc += v.x * cv.x + v.y * cv.y + v.z * cv.z + v.w * cv.w;
    }
    // quad reduce: all 4 lanes of the row end up with the totals
    sx += __shfl_xor(sx, 1); sx += __shfl_xor(sx, 2);
    sc += __shfl_xor(sc, 1); sc += __shfl_xor(sc, 2);
    float nx = sqrtf(sx);
    float inv = 16.f / (nx + EPSV);               // x16 into e4m3
    int* er = (int*)(en8 + (size_t)(s * UTT + row) * DIM);
#pragma unroll
    for (int i = 0; i < 16; ++i)
        er[i * 4 + sub] = pk_fp8(xv[i].x * inv, xv[i].y * inv,
                                 xv[i].z * inv, xv[i].w * inv);
    if (sub == 0) {
        // sim_excl = x.(csum-x) / ((||x||+eps)(||csum-x||+63eps))  (fp32 exact)
        float num = sc - sx;
        float e2 = fmaxf(scc - 2.f * sc + sx, 0.f);
        float sim = num / ((nx + EPSV) * (sqrtf(e2) + (UTT - 1) * EPSV));
        texcl[s * UTT + row] = fmaf(sim, w, b);
    }
}

// K2: fp8 matmul, NO LDS / NO barriers. Block = 4 speakers x one 128-col
// slice; wave = 1 speaker x 128 cols, A fp8-resident in 64 VGPRs, B-frags
// (cincl8, 256 KB = L2-resident) loaded straight from global with one-ntile
// prefetch; 3 waves/EU (launch_bounds(256,3), footprint ~160 < 170 cap: NO
// spill) hide the L2 latency. XCD swizzle keeps a speaker group's en8 slices
// on one XCD. Logits = acc*(w/256) + b (x16 quant on both operands).
__global__ __launch_bounds__(256, 3)
void k_main(const unsigned char* __restrict__ en8,
            const unsigned char* __restrict__ cincl8,
            float* __restrict__ partial,
            const float* __restrict__ wp, const float* __restrict__ bp) {
    int tid = threadIdx.x, wave = tid >> 6, lane = tid & 63;
    int quad = lane >> 4, lx = lane & 15;
    int bid = blockIdx.x;
    int xcd = bid & 7, j = bid >> 3;             // j in [0,256)
    int cs = j & 7;                              // column slice (0..7)
    int sg = xcd + 8 * (j >> 3);                 // speaker group (0..255)
    int sw = sg * 4 + wave;                      // this wave's speaker
    float w = wp[0], b = bp[0];
    float M  = fabsf(w) * 1.0625f + b;           // >= any logit (|sim| <= ~1)
    float wl = w * (LOG2E / 256.f);              // undo x16*x16 quant scale
    float bl = (b - M) * LOG2E;                  // exp(v-M) = exp2(acc*wl + bl)

    // A fragments: lane ℓ holds A[m = ℓ&15][k = (ℓ>>4)*8 .. +8] per (mt,kt)
    const unsigned char* abase = en8 + (size_t)sw * UTT * DIM;
    long af[4][8];
#pragma unroll
    for (int mt = 0; mt < 4; ++mt)
#pragma unroll
        for (int kt = 0; kt < 8; ++kt)
            af[mt][kt] = *(const long*)(abase + (mt * 16 + lx) * DIM + kt * 32 + quad * 8);

    // B fragment base for this lane: col = cs*128 + nt*16 + lx, bytes kt*32+quad*8
    const unsigned char* bbase = cincl8 + (size_t)(cs * 128 + lx) * DIM + quad * 8;

    float l[16];
#pragma unroll
    for (int i = 0; i < 16; ++i) l[i] = 0.f;

    int dnt = (sw >> 4) - cs * 8;                // diag ntile if in [0,8)
    int dlx = sw & 15;

    long bn[8];
#pragma unroll
    for (int kt = 0; kt < 8; ++kt)               // prefetch ntile 0
        bn[kt] = *(const long*)(bbase + kt * 32);

    for (int nt = 0; nt < 8; ++nt) {
        long bf[8];
#pragma unroll
        for (int kt = 0; kt < 8; ++kt) bf[kt] = bn[kt];
        if (nt < 7) {                            // prefetch next ntile (L2-hot)
            const unsigned char* nb = bbase + (size_t)(nt + 1) * 16 * DIM;
#pragma unroll
            for (int kt = 0; kt < 8; ++kt)
                bn[kt] = *(const long*)(nb + kt * 32);
        }
        f32x4 aA[4] = {{0.f,0.f,0.f,0.f},{0.f,0.f,0.f,0.f},
                       {0.f,0.f,0.f,0.f},{0.f,0.f,0.f,0.f}};
        f32x4 aB[4] = {{0.f,0.f,0.f,0.f},{0.f,0.f,0.f,0.f},
                       {0.f,0.f,0.f,0.f},{0.f,0.f,0.f,0.f}};
#pragma unroll
        for (int kt = 0; kt < 4; ++kt) {         // 8 interleaved MFMA chains
            aA[0] = __builtin_amdgcn_mfma_f32_16x16x32_fp8_fp8(af[0][kt], bf[kt], aA[0], 0, 0, 0);
            aA[1] = __builtin_amdgcn_mfma_f32_16x16x32_fp8_fp8(af[1][kt], bf[kt], aA[1], 0, 0, 0);
            aA[2] = __builtin_amdgcn_mfma_f32_16x16x32_fp8_fp8(af[2][kt], bf[kt], aA[2], 0, 0, 0);
            aA[3] = __builtin_amdgcn_mfma_f32_16x16x32_fp8_fp8(af[3][kt], bf[kt], aA[3], 0, 0, 0);
            aB[0] = __builtin_amdgcn_mfma_f32_16x16x32_fp8_fp8(af[0][kt+4], bf[kt+4], aB[0], 0, 0, 0);
            aB[1] = __builtin_amdgcn_mfma_f32_16x16x32_fp8_fp8(af[1][kt+4], bf[kt+4], aB[1], 0, 0, 0);
            aB[2] = __builtin_amdgcn_mfma_f32_16x16x32_fp8_fp8(af[2][kt+4], bf[kt+4], aB[2], 0, 0, 0);
            aB[3] = __builtin_amdgcn_mfma_f32_16x16x32_fp8_fp8(af[3][kt+4], bf[kt+4], aB[3], 0, 0, 0);
        }
#pragma unroll
        for (int mt = 0; mt < 4; ++mt)
#pragma unroll
            for (int r = 0; r < 4; ++r)
                l[mt * 4 + r] += EXP2(fmaf(aA[mt][r] + aB[mt][r], wl, bl));
        if (nt == dnt) {                          // wave-uniform: undo diag col
#pragma unroll
            for (int mt = 0; mt < 4; ++mt)
#pragma unroll
                for (int r = 0; r < 4; ++r) {
                    float e = EXP2(fmaf(aA[mt][r] + aB[mt][r], wl, bl));
                    if (lx == dlx) l[mt * 4 + r] -= e;
                }
        }
    }

    // reduce over the 16 col-lanes; rows live at (quad, mt, r)
#pragma unroll
    for (int o = 1; o < 16; o <<= 1)
#pragma unroll
        for (int i = 0; i < 16; ++i) l[i] += __shfl_xor(l[i], o);
    if (lx == 0)
#pragma unroll
        for (int mt = 0; mt < 4; ++mt)
#pragma unroll
            for (int r = 0; r < 4; ++r)
                partial[(size_t)cs * NROW + (size_t)sw * UTT + mt * 16 + quad * 4 + r]
                    = l[mt * 4 + r];
}

// K3: combine the 8 slice partials per row, logsumexp, mean-reduce.
__global__ __launch_bounds__(256)
void k_final(const float* __restrict__ partial, const float* __restrict__ texcl,
             const float* __restrict__ wp, const float* __restrict__ bp,
             float* __restrict__ out) {
    int row = blockIdx.x * 256 + threadIdx.x;
    float w = wp[0], b = bp[0];
    float M = fabsf(w) * 1.0625f + b;
    float t = 0.f;
#pragma unroll
    for (int sl = 0; sl < NSL; ++sl) t += partial[(size_t)sl * NROW + row];
    float tex = texcl[row];
    float c = (M + __logf(t + EXP2((tex - M) * LOG2E))) - tex;   // lse - target
#pragma unroll
    for (int o = 1; o < 64; o <<= 1) c += __shfl_xor(c, o);
    __shared__ float red[4];
    if ((threadIdx.x & 63) == 0) red[threadIdx.x >> 6] = c;
    __syncthreads();
    if (threadIdx.x == 0)
        atomicAdd(out, (red[0] + red[1] + red[2] + red[3]) * (1.f / NROW));
}

extern "C" void kernel_launch(void* const* d_in, const int* in_sizes, int n_in,
                              void* d_out, int out_size, void* d_ws, size_t ws_size,
                              hipStream_t stream) {
    const float* x  = (const float*)d_in[0];
    const float* wp = (const float*)d_in[1];
    const float* bp = (const float*)d_in[2];
    char* ws = (char*)d_ws;
    unsigned char* cincl8 = (unsigned char*)ws;                     // @0,    256 KB
    float* texcl          = (float*)(ws + (1u << 19));              // @512K, 256 KB
    float* partial        = (float*)(ws + (1u << 20));              // @1M,   2 MB
    unsigned char* en8    = (unsigned char*)(ws + (4u << 20));      // @4M,   16 MB
    float* out = (float*)d_out;

    hipMemsetAsync(d_out, 0, sizeof(float), stream);
    k_prep <<<SPK, 256, 0, stream>>>(x, cincl8, en8, texcl, wp, bp);
    k_main <<<(SPK / 4) * NSL, 256, 0, stream>>>(en8, cincl8, partial, wp, bp);
    k_final<<<NROW / 256, 256, 0, stream>>>(partial, texcl, wp, bp, out);
}

// Round 12
// 149.553 us; speedup vs baseline: 2.6804x; 1.3110x over previous
//
#include <hip/hip_runtime.h>

#define SPK 1024
#define UTT 64
#define DIM 256
#define EPSV 1e-5f
#define NROW (SPK * UTT)
#define NSL 8            // column slices (128 cols each)
#define LOG2E 1.44269504f

typedef __attribute__((ext_vector_type(4))) float f32x4;    // MFMA accumulator

#define EXP2(x) __builtin_amdgcn_exp2f(x)     // bare v_exp_f32, no libm guards

// pack 4 floats -> 4 fp8 e4m3 bytes
__device__ __forceinline__ int pk_fp8(float a, float b, float c, float d) {
    int v = __builtin_amdgcn_cvt_pk_fp8_f32(a, b, 0, false);   // bytes 0,1
    return  __builtin_amdgcn_cvt_pk_fp8_f32(c, d, v, true);    // bytes 2,3
}

// K1: one block (256 thr) per speaker. Phase A: csum + c_incl (fp8, x16 scale)
// + ||csum||^2. Phase B: 4 lanes per row (quad-reduce), x re-read L2-hot,
// writes e_n (fp8, x16 scale) and fp32 diagonal logit texcl = w*sim_excl + b.
__global__ __launch_bounds__(256)
void k_prep(const float* __restrict__ x,
            unsigned char* __restrict__ cincl8,
            unsigned char* __restrict__ en8,
            float* __restrict__ texcl,
            const float* __restrict__ wp, const float* __restrict__ bp) {
    __shared__ float4 sc4[256];
    __shared__ float4 cs4[64];
    __shared__ float sccs;
    int s = blockIdx.x, tid = threadIdx.x;
    int dq = tid & 63, ug = tid >> 6;
    const float4* x4 = (const float4*)(x + (size_t)s * UTT * DIM);

    // Phase A: column sums over the 64 utterances (coalesced 1KB/instr)
    float4 p = {0.f, 0.f, 0.f, 0.f};
#pragma unroll
    for (int i = 0; i < 16; ++i) {
        float4 v = x4[(ug * 16 + i) * 64 + dq];
        p.x += v.x; p.y += v.y; p.z += v.z; p.w += v.w;
    }
    sc4[tid] = p;
    __syncthreads();
    if (tid < 64) {
        float4 a = sc4[dq], b2 = sc4[64 + dq], c = sc4[128 + dq], d = sc4[192 + dq];
        float4 cs = {a.x + b2.x + c.x + d.x, a.y + b2.y + c.y + d.y,
                     a.z + b2.z + c.z + d.z, a.w + b2.w + c.w + d.w};
        cs4[dq] = cs;
        float s2 = cs.x * cs.x + cs.y * cs.y + cs.z * cs.z + cs.w * cs.w;
#pragma unroll
        for (int o = 1; o < 64; o <<= 1) s2 += __shfl_xor(s2, o);
        if (tid == 0) sccs = s2;
        // c_incl = csum/(||csum|| + U*eps), quantized x16 into e4m3
        float inv = 16.f / (sqrtf(s2) + UTT * EPSV);
        ((int*)cincl8)[s * 64 + dq] =
            pk_fp8(cs.x * inv, cs.y * inv, cs.z * inv, cs.w * inv);
    }
    __syncthreads();
    float scc = sccs;
    float w = wp[0], b = bp[0];

    // Phase B: row = tid>>2 (64 rows), sub = tid&3 (4 lanes per row).
    int row = tid >> 2, sub = tid & 3;
    const float4* xr = x4 + row * 64;
    float4 xv[16];
    float sx = 0.f, sc = 0.f;
#pragma unroll
    for (int i = 0; i < 16; ++i) {
        float4 v = xr[i * 4 + sub];
        float4 cv = cs4[i * 4 + sub];
        xv[i] = v;
        sx += v.x * v.x + v.y * v.y + v.z * v.z + v.w * v.w;
        sc += v.x * cv.x + v.y * cv.y + v.z * cv.z + v.w * cv.w;
    }
    // quad reduce: all 4 lanes of the row end up with the totals
    sx += __shfl_xor(sx, 1); sx += __shfl_xor(sx, 2);
    sc += __shfl_xor(sc, 1); sc += __shfl_xor(sc, 2);
    float nx = sqrtf(sx);
    float inv = 16.f / (nx + EPSV);               // x16 into e4m3
    int* er = (int*)(en8 + (size_t)(s * UTT + row) * DIM);
#pragma unroll
    for (int i = 0; i < 16; ++i)
        er[i * 4 + sub] = pk_fp8(xv[i].x * inv, xv[i].y * inv,
                                 xv[i].z * inv, xv[i].w * inv);
    if (sub == 0) {
        // sim_excl = x.(csum-x) / ((||x||+eps)(||csum-x||+63eps))  (fp32 exact)
        float num = sc - sx;
        float e2 = fmaxf(scc - 2.f * sc + sx, 0.f);
        float sim = num / ((nx + EPSV) * (sqrtf(e2) + (UTT - 1) * EPSV));
        texcl[s * UTT + row] = fmaf(sim, w, b);
    }
}

// K2: fp8 matmul. Block = 4 speakers x one 128-col slice; B slice (32 KB fp8)
// staged into LDS ONCE via width-16 global_load_lds (one barrier per block),
// then 8 ntiles of ds_read_b64 + MFMA + exp2. Slot (nt,kt) = 512 B, layout
// [lx][quad][8B] so each lane's staged 16 B is CONTIGUOUS in global (quads
// 2h,2h+1 of one column). fp8 halves af to 64 regs -> 3 blocks/CU
// (launch_bounds(256,3), ~150 regs < 170 cap, 96 KB LDS) hides stalls.
// XCD swizzle keeps a speaker group's slices on one XCD (L2-hot en8).
__global__ __launch_bounds__(256, 3)
void k_main(const unsigned char* __restrict__ en8,
            const unsigned char* __restrict__ cincl8,
            float* __restrict__ partial,
            const float* __restrict__ wp, const float* __restrict__ bp) {
    __shared__ unsigned char Bs[64 * 512];       // 64 slots x 512 B = 32 KB
    int tid = threadIdx.x, wave = tid >> 6, lane = tid & 63;
    int quad = lane >> 4, lx = lane & 15;
    int bid = blockIdx.x;
    int xcd = bid & 7, j = bid >> 3;             // j in [0,256)
    int cs = j & 7;                              // column slice (0..7)
    int sg = xcd + 8 * (j >> 3);                 // speaker group (0..255)
    int sw = sg * 4 + wave;                      // this wave's speaker
    float w = wp[0], b = bp[0];
    float M  = fabsf(w) * 1.0625f + b;           // >= any logit (|sim| <= ~1)
    float wl = w * (LOG2E / 256.f);              // undo x16*x16 quant scale
    float bl = (b - M) * LOG2E;                  // exp(v-M) = exp2(acc*wl + bl)

    // stage B: wave w covers ntiles 2w,2w+1; issue (nt,kp) writes slots
    // nt*8+kp*2 .. +1 (1 KB): lane ℓ: kt = kp*2+(ℓ>>5), m=ℓ&31, col lx'=m>>1,
    // h=m&1 -> global col (cs*128+nt*16+lx') bytes kt*32+h*16 .. +16.
#pragma unroll
    for (int nti = 0; nti < 2; ++nti) {
        int nt = wave * 2 + nti;
#pragma unroll
        for (int kp = 0; kp < 4; ++kp) {
            int kt = kp * 2 + (lane >> 5);
            int m = lane & 31, slx = m >> 1, h = m & 1;
            const unsigned char* g = cincl8 +
                (size_t)(cs * 128 + nt * 16 + slx) * DIM + kt * 32 + h * 16;
            __builtin_amdgcn_global_load_lds(
                (const __attribute__((address_space(1))) void*)g,
                (__attribute__((address_space(3))) void*)(Bs + (nt * 8 + kp * 2) * 512),
                16, 0, 0);
        }
    }

    // A fragments: lane ℓ holds A[m = ℓ&15][k = (ℓ>>4)*8 .. +8] per (mt,kt)
    const unsigned char* abase = en8 + (size_t)sw * UTT * DIM;
    long af[4][8];
#pragma unroll
    for (int mt = 0; mt < 4; ++mt)
#pragma unroll
        for (int kt = 0; kt < 8; ++kt)
            af[mt][kt] = *(const long*)(abase + (mt * 16 + lx) * DIM + kt * 32 + quad * 8);

    float l[16];
#pragma unroll
    for (int i = 0; i < 16; ++i) l[i] = 0.f;

    __syncthreads();                             // staging complete (only barrier)

    int dnt = (sw >> 4) - cs * 8;                // diag ntile if in [0,8)
    int dlx = sw & 15;

    for (int nt = 0; nt < 8; ++nt) {
        long bf[8];
#pragma unroll
        for (int kt = 0; kt < 8; ++kt)
            bf[kt] = *(const long*)(Bs + (nt * 8 + kt) * 512 + lx * 32 + quad * 8);
        f32x4 aA[4] = {{0.f,0.f,0.f,0.f},{0.f,0.f,0.f,0.f},
                       {0.f,0.f,0.f,0.f},{0.f,0.f,0.f,0.f}};
        f32x4 aB[4] = {{0.f,0.f,0.f,0.f},{0.f,0.f,0.f,0.f},
                       {0.f,0.f,0.f,0.f},{0.f,0.f,0.f,0.f}};
#pragma unroll
        for (int kt = 0; kt < 4; ++kt) {         // 8 interleaved MFMA chains
            aA[0] = __builtin_amdgcn_mfma_f32_16x16x32_fp8_fp8(af[0][kt], bf[kt], aA[0], 0, 0, 0);
            aA[1] = __builtin_amdgcn_mfma_f32_16x16x32_fp8_fp8(af[1][kt], bf[kt], aA[1], 0, 0, 0);
            aA[2] = __builtin_amdgcn_mfma_f32_16x16x32_fp8_fp8(af[2][kt], bf[kt], aA[2], 0, 0, 0);
            aA[3] = __builtin_amdgcn_mfma_f32_16x16x32_fp8_fp8(af[3][kt], bf[kt], aA[3], 0, 0, 0);
            aB[0] = __builtin_amdgcn_mfma_f32_16x16x32_fp8_fp8(af[0][kt+4], bf[kt+4], aB[0], 0, 0, 0);
            aB[1] = __builtin_amdgcn_mfma_f32_16x16x32_fp8_fp8(af[1][kt+4], bf[kt+4], aB[1], 0, 0, 0);
            aB[2] = __builtin_amdgcn_mfma_f32_16x16x32_fp8_fp8(af[2][kt+4], bf[kt+4], aB[2], 0, 0, 0);
            aB[3] = __builtin_amdgcn_mfma_f32_16x16x32_fp8_fp8(af[3][kt+4], bf[kt+4], aB[3], 0, 0, 0);
        }
#pragma unroll
        for (int mt = 0; mt < 4; ++mt)
#pragma unroll
            for (int r = 0; r < 4; ++r)
                l[mt * 4 + r] += EXP2(fmaf(aA[mt][r] + aB[mt][r], wl, bl));
        if (nt == dnt) {                          // wave-uniform: undo diag col
#pragma unroll
            for (int mt = 0; mt < 4; ++mt)
#pragma unroll
                for (int r = 0; r < 4; ++r) {
                    float e = EXP2(fmaf(aA[mt][r] + aB[mt][r], wl, bl));
                    if (lx == dlx) l[mt * 4 + r] -= e;
                }
        }
    }

    // reduce over the 16 col-lanes; rows live at (quad, mt, r)
#pragma unroll
    for (int o = 1; o < 16; o <<= 1)
#pragma unroll
        for (int i = 0; i < 16; ++i) l[i] += __shfl_xor(l[i], o);
    if (lx == 0)
#pragma unroll
        for (int mt = 0; mt < 4; ++mt)
#pragma unroll
            for (int r = 0; r < 4; ++r)
                partial[(size_t)cs * NROW + (size_t)sw * UTT + mt * 16 + quad * 4 + r]
                    = l[mt * 4 + r];
}

// K3: combine the 8 slice partials per row, logsumexp, mean-reduce.
__global__ __launch_bounds__(256)
void k_final(const float* __restrict__ partial, const float* __restrict__ texcl,
             const float* __restrict__ wp, const float* __restrict__ bp,
             float* __restrict__ out) {
    int row = blockIdx.x * 256 + threadIdx.x;
    float w = wp[0], b = bp[0];
    float M = fabsf(w) * 1.0625f + b;
    float t = 0.f;
#pragma unroll
    for (int sl = 0; sl < NSL; ++sl) t += partial[(size_t)sl * NROW + row];
    float tex = texcl[row];
    float c = (M + __logf(t + EXP2((tex - M) * LOG2E))) - tex;   // lse - target
#pragma unroll
    for (int o = 1; o < 64; o <<= 1) c += __shfl_xor(c, o);
    __shared__ float red[4];
    if ((threadIdx.x & 63) == 0) red[threadIdx.x >> 6] = c;
    __syncthreads();
    if (threadIdx.x == 0)
        atomicAdd(out, (red[0] + red[1] + red[2] + red[3]) * (1.f / NROW));
}

extern "C" void kernel_launch(void* const* d_in, const int* in_sizes, int n_in,
                              void* d_out, int out_size, void* d_ws, size_t ws_size,
                              hipStream_t stream) {
    const float* x  = (const float*)d_in[0];
    const float* wp = (const float*)d_in[1];
    const float* bp = (const float*)d_in[2];
    char* ws = (char*)d_ws;
    unsigned char* cincl8 = (unsigned char*)ws;                     // @0,    256 KB
    float* texcl          = (float*)(ws + (1u << 19));              // @512K, 256 KB
    float* partial        = (float*)(ws + (1u << 20));              // @1M,   2 MB
    unsigned char* en8    = (unsigned char*)(ws + (4u << 20));      // @4M,   16 MB
    float* out = (float*)d_out;

    hipMemsetAsync(d_out, 0, sizeof(float), stream);
    k_prep <<<SPK, 256, 0, stream>>>(x, cincl8, en8, texcl, wp, bp);
    k_main <<<(SPK / 4) * NSL, 256, 0, stream>>>(en8, cincl8, partial, wp, bp);
    k_final<<<NROW / 256, 256, 0, stream>>>(partial, texcl, wp, bp, out);
}

// Round 13
// 143.131 us; speedup vs baseline: 2.8007x; 1.0449x over previous
//
#include <hip/hip_runtime.h>

#define SPK 1024
#define UTT 64
#define DIM 256
#define EPSV 1e-5f
#define NROW (SPK * UTT)
#define NSL 8            // column slices (128 cols each)
#define LOG2E 1.44269504f

typedef __attribute__((ext_vector_type(4))) float f32x4;    // MFMA accumulator
typedef __attribute__((ext_vector_type(2))) long long2v;    // 16 B = 2 fp8 ktile frags

#define EXP2(x) __builtin_amdgcn_exp2f(x)     // bare v_exp_f32, no libm guards

// pack 4 floats -> 4 fp8 e4m3 bytes
__device__ __forceinline__ int pk_fp8(float a, float b, float c, float d) {
    int v = __builtin_amdgcn_cvt_pk_fp8_f32(a, b, 0, false);   // bytes 0,1
    return  __builtin_amdgcn_cvt_pk_fp8_f32(c, d, v, true);    // bytes 2,3
}

// MFMA-fragment byte order for a 256-byte fp8 row/column:
// unit (r,quad) (16 B) = k-bytes [2r*32+quad*8 .. +8] ++ [(2r+1)*32+quad*8 .. +8].
// fragIdx maps original int-group g (bytes g*4..+4) -> stored int index.
__device__ __forceinline__ int fragIdx(int g) {
    return ((g >> 4) * 4 + ((g & 7) >> 1)) * 4 + ((g >> 3) & 1) * 2 + (g & 1);
}

// K1: one block (256 thr) per speaker. Phase A: csum + c_incl (fp8 x16,
// fragment order) + ||csum||^2. Phase B: 4 lanes per row (quad-reduce),
// x re-read L2-hot, writes e_n (fp8 x16, fragment order) and fp32 diagonal
// logit texcl = w*sim_excl + b.
__global__ __launch_bounds__(256)
void k_prep(const float* __restrict__ x,
            unsigned char* __restrict__ cincl8,
            unsigned char* __restrict__ en8,
            float* __restrict__ texcl,
            const float* __restrict__ wp, const float* __restrict__ bp) {
    __shared__ float4 sc4[256];
    __shared__ float4 cs4[64];
    __shared__ float sccs;
    int s = blockIdx.x, tid = threadIdx.x;
    int dq = tid & 63, ug = tid >> 6;
    const float4* x4 = (const float4*)(x + (size_t)s * UTT * DIM);

    // Phase A: column sums over the 64 utterances (coalesced 1KB/instr)
    float4 p = {0.f, 0.f, 0.f, 0.f};
#pragma unroll
    for (int i = 0; i < 16; ++i) {
        float4 v = x4[(ug * 16 + i) * 64 + dq];
        p.x += v.x; p.y += v.y; p.z += v.z; p.w += v.w;
    }
    sc4[tid] = p;
    __syncthreads();
    if (tid < 64) {
        float4 a = sc4[dq], b2 = sc4[64 + dq], c = sc4[128 + dq], d = sc4[192 + dq];
        float4 cs = {a.x + b2.x + c.x + d.x, a.y + b2.y + c.y + d.y,
                     a.z + b2.z + c.z + d.z, a.w + b2.w + c.w + d.w};
        cs4[dq] = cs;
        float s2 = cs.x * cs.x + cs.y * cs.y + cs.z * cs.z + cs.w * cs.w;
#pragma unroll
        for (int o = 1; o < 64; o <<= 1) s2 += __shfl_xor(s2, o);
        if (tid == 0) sccs = s2;
        // c_incl = csum/(||csum|| + U*eps), quantized x16 into e4m3
        float inv = 16.f / (sqrtf(s2) + UTT * EPSV);
        ((int*)cincl8)[s * 64 + fragIdx(dq)] =
            pk_fp8(cs.x * inv, cs.y * inv, cs.z * inv, cs.w * inv);
    }
    __syncthreads();
    float scc = sccs;
    float w = wp[0], b = bp[0];

    // Phase B: row = tid>>2 (64 rows), sub = tid&3 (4 lanes per row).
    int row = tid >> 2, sub = tid & 3;
    const float4* xr = x4 + row * 64;
    float4 xv[16];
    float sx = 0.f, sc = 0.f;
#pragma unroll
    for (int i = 0; i < 16; ++i) {
        float4 v = xr[i * 4 + sub];
        float4 cv = cs4[i * 4 + sub];
        xv[i] = v;
        sx += v.x * v.x + v.y * v.y + v.z * v.z + v.w * v.w;
        sc += v.x * cv.x + v.y * cv.y + v.z * cv.z + v.w * cv.w;
    }
    // quad reduce: all 4 lanes of the row end up with the totals
    sx += __shfl_xor(sx, 1); sx += __shfl_xor(sx, 2);
    sc += __shfl_xor(sc, 1); sc += __shfl_xor(sc, 2);
    float nx = sqrtf(sx);
    float inv = 16.f / (nx + EPSV);               // x16 into e4m3
    int* er = (int*)(en8 + (size_t)(s * UTT + row) * DIM);
#pragma unroll
    for (int i = 0; i < 16; ++i)
        er[fragIdx(i * 4 + sub)] = pk_fp8(xv[i].x * inv, xv[i].y * inv,
                                          xv[i].z * inv, xv[i].w * inv);
    if (sub == 0) {
        // sim_excl = x.(csum-x) / ((||x||+eps)(||csum-x||+63eps))  (fp32 exact)
        float num = sc - sx;
        float e2 = fmaxf(scc - 2.f * sc + sx, 0.f);
        float sim = num / ((nx + EPSV) * (sqrtf(e2) + (UTT - 1) * EPSV));
        texcl[s * UTT + row] = fmaf(sim, w, b);
    }
}

// K2: fp8 matmul. Block = 4 speakers x one 128-col slice. Both operands are
// stored in MFMA-fragment order, so: staging = per-lane 16 B global_load_lds
// into region+lane*16; hot loop = ds_read_b128 at lane*16 (the verified
// ZERO-conflict pattern, R8) giving 2 ktiles per read; A-frags = global b128.
// One barrier per block; XCD swizzle keeps a group's en8 on one XCD.
__global__ __launch_bounds__(256, 3)
void k_main(const unsigned char* __restrict__ en8,
            const unsigned char* __restrict__ cincl8,
            float* __restrict__ partial,
            const float* __restrict__ wp, const float* __restrict__ bp) {
    __shared__ unsigned char Bs[32 * 1024];      // 32 regions (nt,r) x 1 KB
    int tid = threadIdx.x, wave = tid >> 6, lane = tid & 63;
    int quad = lane >> 4, lx = lane & 15;
    int bid = blockIdx.x;
    int xcd = bid & 7, j = bid >> 3;             // j in [0,256)
    int cs = j & 7;                              // column slice (0..7)
    int sg = xcd + 8 * (j >> 3);                 // speaker group (0..255)
    int sw = sg * 4 + wave;                      // this wave's speaker
    float w = wp[0], b = bp[0];
    float M  = fabsf(w) * 1.0625f + b;           // >= any logit (|sim| <= ~1)
    float wl = w * (LOG2E / 256.f);              // undo x16*x16 quant scale
    float bl = (b - M) * LOG2E;                  // exp(v-M) = exp2(acc*wl + bl)

    // stage B: region (nt,r) = 1 KB at (nt*4+r)*1024; lane ℓ supplies col
    // cs*128+nt*16+(ℓ&15), unit (r, ℓ>>4) -> LDS region + ℓ*16 (HW rule).
#pragma unroll
    for (int nti = 0; nti < 2; ++nti) {
        int nt = wave * 2 + nti;
#pragma unroll
        for (int r = 0; r < 4; ++r) {
            const unsigned char* g = cincl8 +
                (size_t)(cs * 128 + nt * 16 + lx) * DIM + (r * 4 + quad) * 16;
            __builtin_amdgcn_global_load_lds(
                (const __attribute__((address_space(1))) void*)g,
                (__attribute__((address_space(3))) void*)(Bs + (nt * 4 + r) * 1024),
                16, 0, 0);
        }
    }

    // A fragments (fragment-order rows): af2[mt][r] = ktiles (2r, 2r+1)
    const unsigned char* abase = en8 + (size_t)sw * UTT * DIM;
    long2v af2[4][4];
#pragma unroll
    for (int mt = 0; mt < 4; ++mt)
#pragma unroll
        for (int r = 0; r < 4; ++r)
            af2[mt][r] = *(const long2v*)(abase + (mt * 16 + lx) * DIM + (r * 4 + quad) * 16);

    float l[16];
#pragma unroll
    for (int i = 0; i < 16; ++i) l[i] = 0.f;

    __syncthreads();                             // staging complete (only barrier)

    int dnt = (sw >> 4) - cs * 8;                // diag ntile if in [0,8)
    int dlx = sw & 15;

    for (int nt = 0; nt < 8; ++nt) {
        long2v bf2[4];
#pragma unroll
        for (int r = 0; r < 4; ++r)
            bf2[r] = *(const long2v*)(Bs + (nt * 4 + r) * 1024 + lane * 16);
        f32x4 aA[4] = {{0.f,0.f,0.f,0.f},{0.f,0.f,0.f,0.f},
                       {0.f,0.f,0.f,0.f},{0.f,0.f,0.f,0.f}};
        f32x4 aB[4] = {{0.f,0.f,0.f,0.f},{0.f,0.f,0.f,0.f},
                       {0.f,0.f,0.f,0.f},{0.f,0.f,0.f,0.f}};
#pragma unroll
        for (int r = 0; r < 2; ++r) {            // 8 interleaved MFMA chains
#pragma unroll
            for (int mt = 0; mt < 4; ++mt) {
                aA[mt] = __builtin_amdgcn_mfma_f32_16x16x32_fp8_fp8(af2[mt][r].x,   bf2[r].x,   aA[mt], 0, 0, 0);
                aB[mt] = __builtin_amdgcn_mfma_f32_16x16x32_fp8_fp8(af2[mt][r+2].x, bf2[r+2].x, aB[mt], 0, 0, 0);
            }
#pragma unroll
            for (int mt = 0; mt < 4; ++mt) {
                aA[mt] = __builtin_amdgcn_mfma_f32_16x16x32_fp8_fp8(af2[mt][r].y,   bf2[r].y,   aA[mt], 0, 0, 0);
                aB[mt] = __builtin_amdgcn_mfma_f32_16x16x32_fp8_fp8(af2[mt][r+2].y, bf2[r+2].y, aB[mt], 0, 0, 0);
            }
        }
#pragma unroll
        for (int mt = 0; mt < 4; ++mt)
#pragma unroll
            for (int r = 0; r < 4; ++r)
                l[mt * 4 + r] += EXP2(fmaf(aA[mt][r] + aB[mt][r], wl, bl));
        if (nt == dnt) {                          // wave-uniform: undo diag col
#pragma unroll
            for (int mt = 0; mt < 4; ++mt)
#pragma unroll
                for (int r = 0; r < 4; ++r) {
                    float e = EXP2(fmaf(aA[mt][r] + aB[mt][r], wl, bl));
                    if (lx == dlx) l[mt * 4 + r] -= e;
                }
        }
    }

    // reduce over the 16 col-lanes; rows live at (quad, mt, r)
#pragma unroll
    for (int o = 1; o < 16; o <<= 1)
#pragma unroll
        for (int i = 0; i < 16; ++i) l[i] += __shfl_xor(l[i], o);
    if (lx == 0)
#pragma unroll
        for (int mt = 0; mt < 4; ++mt)
#pragma unroll
            for (int r = 0; r < 4; ++r)
                partial[(size_t)cs * NROW + (size_t)sw * UTT + mt * 16 + quad * 4 + r]
                    = l[mt * 4 + r];
}

// K3: combine the 8 slice partials per row, logsumexp, mean-reduce.
__global__ __launch_bounds__(256)
void k_final(const float* __restrict__ partial, const float* __restrict__ texcl,
             const float* __restrict__ wp, const float* __restrict__ bp,
             float* __restrict__ out) {
    int row = blockIdx.x * 256 + threadIdx.x;
    float w = wp[0], b = bp[0];
    float M = fabsf(w) * 1.0625f + b;
    float t = 0.f;
#pragma unroll
    for (int sl = 0; sl < NSL; ++sl) t += partial[(size_t)sl * NROW + row];
    float tex = texcl[row];
    float c = (M + __logf(t + EXP2((tex - M) * LOG2E))) - tex;   // lse - target
#pragma unroll
    for (int o = 1; o < 64; o <<= 1) c += __shfl_xor(c, o);
    __shared__ float red[4];
    if ((threadIdx.x & 63) == 0) red[threadIdx.x >> 6] = c;
    __syncthreads();
    if (threadIdx.x == 0)
        atomicAdd(out, (red[0] + red[1] + red[2] + red[3]) * (1.f / NROW));
}

extern "C" void kernel_launch(void* const* d_in, const int* in_sizes, int n_in,
                              void* d_out, int out_size, void* d_ws, size_t ws_size,
                              hipStream_t stream) {
    const float* x  = (const float*)d_in[0];
    const float* wp = (const float*)d_in[1];
    const float* bp = (const float*)d_in[2];
    char* ws = (char*)d_ws;
    unsigned char* cincl8 = (unsigned char*)ws;                     // @0,    256 KB
    float* texcl          = (float*)(ws + (1u << 19));              // @512K, 256 KB
    float* partial        = (float*)(ws + (1u << 20));              // @1M,   2 MB
    unsigned char* en8    = (unsigned char*)(ws + (4u << 20));      // @4M,   16 MB
    float* out = (float*)d_out;

    hipMemsetAsync(d_out, 0, sizeof(float), stream);
    k_prep <<<SPK, 256, 0, stream>>>(x, cincl8, en8, texcl, wp, bp);
    k_main <<<(SPK / 4) * NSL, 256, 0, stream>>>(en8, cincl8, partial, wp, bp);
    k_final<<<NROW / 256, 256, 0, stream>>>(partial, texcl, wp, bp, out);
}